// Round 15
// baseline (175.379 us; speedup 1.0000x reference)
//
#include <hip/hip_runtime.h>
#include <stdint.h>
#include <stddef.h>

typedef __attribute__((ext_vector_type(8))) short s16x8;
typedef __attribute__((ext_vector_type(4))) short s16x4;
typedef __attribute__((ext_vector_type(4))) float f32x4;

#define B_  2
#define T_  2048
#define E_  1024
#define H_  16
#define E3_ 3072

// fp32 -> bf16, round-to-nearest-even
__device__ __forceinline__ short f2bf(float f) {
  union { float f; uint32_t u; } v; v.f = f;
  uint32_t u = v.u;
  return (short)((u + 0x7FFFu + ((u >> 16) & 1u)) >> 16);
}

// async global->LDS, 16B per lane; lds dest = wave-uniform base + lane*16
__device__ __forceinline__ void gload_lds16(const short* g, short* l) {
  __builtin_amdgcn_global_load_lds(
      (__attribute__((address_space(1))) void*)(const_cast<short*>(g)),
      (__attribute__((address_space(3))) void*)(l), 16, 0, 0);
}

// ---------------- merged cast kernel (x, w_qkv, w_proj in one launch) -------
// Q-rows of w_qkv (first E rows) pre-scaled by log2(e)/8 so attention can
// use raw v_exp_f32 directly on MFMA output.
__global__ void castk_all(const float* __restrict__ x, const float* __restrict__ wqkv,
                          const float* __restrict__ wproj, short* __restrict__ xb,
                          short* __restrict__ wqkvb, short* __restrict__ wprojb) {
  const int bid = blockIdx.x;
  const float* in; short* out; int i; float sc = 1.0f;
  if (bid < 4096)      { in = x;     out = xb;     i = bid * 256 + threadIdx.x; }
  else if (bid < 7168) { in = wqkv;  out = wqkvb;  i = (bid - 4096) * 256 + threadIdx.x;
                         if (i < 262144) sc = 0.18033688011112042f; }
  else                 { in = wproj; out = wprojb; i = (bid - 7168) * 256 + threadIdx.x; }
  const float4 v = ((const float4*)in)[i];
  s16x4 o;
  o[0] = f2bf(v.x * sc); o[1] = f2bf(v.y * sc);
  o[2] = f2bf(v.z * sc); o[3] = f2bf(v.w * sc);
  ((s16x4*)out)[i] = o;
}

// ---------------- NT GEMM 128^2 (used for proj only) ------------------------
template <int MODE>
__global__ void gemm_nt_128(const short* __restrict__ A, const short* __restrict__ B,
                            void* __restrict__ Cv, short* __restrict__ vt,
                            int M, int N, int K) {
  __shared__ short As[128 * 32];
  __shared__ short Bs[128 * 32];
  const int tid  = threadIdx.x;
  const int lane = tid & 63;
  const int w    = tid >> 6;
  const int quad = lane >> 4;
  const int l16  = lane & 15;
  const int wm   = (w >> 1) * 64;
  const int wn   = (w & 1) * 64;
  const int bm   = blockIdx.y * 128;
  const int bn   = blockIdx.x * 128;

  f32x4 acc[4][4];
#pragma unroll
  for (int i = 0; i < 4; i++)
#pragma unroll
    for (int j = 0; j < 4; j++) acc[i][j] = (f32x4){0.f, 0.f, 0.f, 0.f};

  const int srow = w * 32 + (lane >> 2);
  const int scol = (lane & 3) * 8;
  const short* gA = A + (size_t)(bm + srow) * K + scol;
  const short* gB = B + (size_t)(bn + srow) * K + scol;
  short* lA = As + (w * 32) * 32;
  short* lB = Bs + (w * 32) * 32;

  for (int k0 = 0; k0 < K; k0 += 32) {
    __syncthreads();
    gload_lds16(gA + k0,          lA);
    gload_lds16(gA + 16 * K + k0, lA + 16 * 32);
    gload_lds16(gB + k0,          lB);
    gload_lds16(gB + 16 * K + k0, lB + 16 * 32);
    __syncthreads();

    s16x8 a[4], b[4];
#pragma unroll
    for (int i = 0; i < 4; i++)
      a[i] = *(const s16x8*)&As[(wm + i * 16 + l16) * 32 + quad * 8];
#pragma unroll
    for (int j = 0; j < 4; j++)
      b[j] = *(const s16x8*)&Bs[(wn + j * 16 + l16) * 32 + quad * 8];
#pragma unroll
    for (int i = 0; i < 4; i++)
#pragma unroll
      for (int j = 0; j < 4; j++)
        acc[i][j] = __builtin_amdgcn_mfma_f32_16x16x32_bf16(a[i], b[j], acc[i][j], 0, 0, 0);
  }

#pragma unroll
  for (int i = 0; i < 4; i++) {
    const int row0 = bm + wm + i * 16 + quad * 4;
#pragma unroll
    for (int j = 0; j < 4; j++) {
      const int col = bn + wn + j * 16 + l16;
#pragma unroll
      for (int r = 0; r < 4; r++) {
        const size_t idx = (size_t)(row0 + r) * N + col;
        if (MODE == 2) ((short*)Cv)[idx] = f2bf(acc[i][j][r]);
        else           ((float*)Cv)[idx] = acc[i][j][r];
      }
    }
  }
}

// ---------------- 256^2 BK=64 phased GEMM for the qkv projection ------------
// R15: the qkv GEMM was at ~860 TF = 95% of the m97-structure ceiling; the
// documented better structure is the 256^2 phased schedule (1563 TF verified
// in learn_hip m201; naive 2-phase 256^2 REGRESSES to ~607 per m233, so the
// phase-interleaved form with raw s_barrier and no per-phase vmcnt drain is
// required). This is a 4-phase/K-tile variant:
//  * 512 thr / 8 waves (2M x 4N), per-wave 128x64 out, BK=64, 16 K-iters.
//  * LDS 128KB: As[2][256*64] + Bs[2][256*64], double-buffered.
//  * Per iter, 4 quadrant-phases: {2 staging gloads (next tile, spread
//    2/phase) || ds_read (B-frags 8 in phase0 + A-quadrant 4) || 16 MFMA ||
//    raw s_barrier}. ONE vmcnt(0) per iter at phase-3 end: >=6 of 8 staging
//    loads get a full iteration (~2500 cyc) of latency cover.
//  * Overwrite safety: stage into buf[c^1] (read at iter t-1) is issued
//    after the barrier that post-dates all its reads; DMA visibility via
//    per-wave vmcnt(0) before the shared barrier.
//  * Bank-conflict-free LDS via the attn kernel's VERIFIED chunk-XOR scheme
//    (pre-swizzled global source sgc + ^swz reads; measured 0 conflicts).
//  * Epilogue = existing MODE-2 semantics at 256^2 indexing: V col-tiles
//    (bn >= 2E) write transposed vt, Q/K tiles write bf16 qkv.
__global__ void __launch_bounds__(512, 2)
gemm256_qkv(const short* __restrict__ A, const short* __restrict__ B,
            short* __restrict__ qkv, short* __restrict__ vt) {
  __shared__ short As[2][256 * 64];  // 64 KB
  __shared__ short Bs[2][256 * 64];  // 64 KB
  const int tid  = threadIdx.x;
  const int lane = tid & 63;
  const int w    = tid >> 6;          // 0..7
  const int quad = lane >> 4;
  const int l16  = lane & 15;
  const int wm   = (w >> 2) * 128;    // 0 / 128
  const int wn   = (w & 3) * 64;      // 0..192
  const int bm   = blockIdx.y * 256;
  const int bn   = blockIdx.x * 256;
  const int srl  = lane >> 3;
  const int sgc  = ((lane & 7) ^ srl) * 8;
  const int swz  = l16 & 7;
  const int K    = 1024;

  const short* gA = A + (size_t)bm * K + sgc;
  const short* gB = B + (size_t)bn * K + sgc;

  f32x4 acc[8][4];
#pragma unroll
  for (int i = 0; i < 8; i++)
#pragma unroll
    for (int j = 0; j < 4; j++) acc[i][j] = (f32x4){0.f, 0.f, 0.f, 0.f};

  auto stageA = [&](int kt1, int bfb, int i0) {
#pragma unroll
    for (int i = i0; i < i0 + 2; i++) {
      const int r8 = w * 32 + i * 8;
      gload_lds16(gA + (size_t)(r8 + srl) * K + kt1 * 64, &As[bfb][r8 * 64]);
    }
  };
  auto stageB = [&](int kt1, int bfb, int i0) {
#pragma unroll
    for (int i = i0; i < i0 + 2; i++) {
      const int r8 = w * 32 + i * 8;
      gload_lds16(gB + (size_t)(r8 + srl) * K + kt1 * 64, &Bs[bfb][r8 * 64]);
    }
  };

  // prologue: stage K-tile 0 into buffer 0 (8 gloads/wave), drain, barrier
  stageA(0, 0, 0); stageA(0, 0, 2);
  stageB(0, 0, 0); stageB(0, 0, 2);
  __asm volatile("s_waitcnt vmcnt(0)" ::: "memory");
  __builtin_amdgcn_s_barrier();

#pragma unroll 1
  for (int kt = 0; kt < 16; kt++) {
    const int c = kt & 1;
    const bool pre = (kt + 1 < 16);
    const short* Ac = &As[c][0];
    const short* Bc = &Bs[c][0];

    s16x8 bf_[4][2];  // B fragments, read in phase 0, live all phases
#pragma unroll
    for (int q = 0; q < 4; q++) {
      // staging pair for next K-tile into buf[c^1] (read at iter kt-1; all
      // its reads completed before the barrier we just crossed)
      if (pre) {
        if (q == 0)      stageA(kt + 1, c ^ 1, 0);
        else if (q == 1) stageA(kt + 1, c ^ 1, 2);
        else if (q == 2) stageB(kt + 1, c ^ 1, 0);
        else             stageB(kt + 1, c ^ 1, 2);
      }
      if (q == 0) {
#pragma unroll
        for (int ni = 0; ni < 4; ni++)
#pragma unroll
          for (int kk = 0; kk < 2; kk++)
            bf_[ni][kk] = *(const s16x8*)&Bc[(wn + ni * 16 + l16) * 64 + (((kk * 4 + quad) ^ swz) * 8)];
      }
      // A fragments for this quadrant (rows 2q*16 .. 2q*16+31 of wave tile)
      s16x8 af[2][2];
#pragma unroll
      for (int m2 = 0; m2 < 2; m2++)
#pragma unroll
        for (int kk = 0; kk < 2; kk++)
          af[m2][kk] = *(const s16x8*)&Ac[(wm + (2 * q + m2) * 16 + l16) * 64 + (((kk * 4 + quad) ^ swz) * 8)];

      __builtin_amdgcn_s_setprio(1);
#pragma unroll
      for (int kk = 0; kk < 2; kk++)
#pragma unroll
        for (int m2 = 0; m2 < 2; m2++)
#pragma unroll
          for (int ni = 0; ni < 4; ni++)
            acc[2 * q + m2][ni] = __builtin_amdgcn_mfma_f32_16x16x32_bf16(
                af[m2][kk], bf_[ni][kk], acc[2 * q + m2][ni], 0, 0, 0);
      __builtin_amdgcn_s_setprio(0);

      if (q == 3) {
        // all reads of buf[c] done; my next-tile DMAs must land before the
        // barrier so every wave sees them next iter. >=6 of 8 loads have a
        // full iteration of cover; never drained mid-iteration.
        if (pre) {
          __asm volatile("s_waitcnt vmcnt(0)" ::: "memory");
          __builtin_amdgcn_s_barrier();
        }
      } else {
        __builtin_amdgcn_s_barrier();
      }
    }
  }

  // epilogue (MODE-2 semantics): V col-tiles -> transposed vt; Q/K -> qkv
  if (bn >= 2 * E_) {
#pragma unroll
    for (int i = 0; i < 8; i++) {
      const int token = bm + wm + i * 16 + quad * 4;
      const int bb = token >> 11, t = token & (T_ - 1);
#pragma unroll
      for (int j = 0; j < 4; j++) {
        const int col = bn + wn + j * 16 + l16 - 2 * E_;  // h*64 + d
        s16x4 pk;
#pragma unroll
        for (int r = 0; r < 4; r++) pk[r] = f2bf(acc[i][j][r]);
        *(s16x4*)&vt[((size_t)(bb * H_ + (col >> 6)) * 64 + (col & 63)) * T_ + t] = pk;
      }
    }
  } else {
#pragma unroll
    for (int i = 0; i < 8; i++) {
      const int row0 = bm + wm + i * 16 + quad * 4;
#pragma unroll
      for (int j = 0; j < 4; j++) {
        const int col = bn + wn + j * 16 + l16;
#pragma unroll
        for (int r = 0; r < 4; r++)
          qkv[(size_t)(row0 + r) * E3_ + col] = f2bf(acc[i][j][r]);
      }
    }
  }
}

// ---------------- flash attention (R12, best verified — unchanged) ----------
__global__ void __launch_bounds__(256, 4)
attn_kernel(const short* __restrict__ qkv, const short* __restrict__ vt,
            short* __restrict__ attout) {
  __shared__ short Ks[2][64 * 64];  // [kv_pos][d], 16B-chunk swizzled, sigma row order
  __shared__ short Vs[2][64 * 64];  // [d][kv], 16B-chunk swizzled, linear kv
  const int tid  = threadIdx.x;
  const int lane = tid & 63;
  const int w    = tid >> 6;
  const int quad = lane >> 4;
  const int l16  = lane & 15;
  const int bh = blockIdx.x;
  const int b = bh >> 4, h = bh & 15;
  // LPT snake mapping: longest q-tiles dispatched first, per-CU sum uniform
  const int ya = blockIdx.y & 7, yb = blockIdx.y >> 3;
  const int qt = (3 - yb) * 8 + ((yb & 1) ? ya : (7 - ya));
  const int q0b = qt * 64;
  const int q0w = q0b + w * 16;
  const float NEG_INF = -__builtin_inff();

  const int srl = lane >> 3;
  const int sgc = ((lane & 7) ^ srl) * 8;
  const short* gK = qkv + (size_t)(b * T_) * E3_ + E_ + h * 64 + sgc;
  const short* gV = vt + (size_t)(bh * 64) * T_ + sgc;
  const int swz = (l16 & 7);

  s16x8 ones;
#pragma unroll
  for (int i = 0; i < 8; i++) ones[i] = (short)0x3F80;  // bf16 1.0

  auto stage = [&](int kv0s, int bf) {
#pragma unroll
    for (int i = 0; i < 2; i++) {
      const int r8 = w * 16 + i * 8;          // LDS row-chunk base
      const int rowp = r8 + srl;              // LDS row position
      // sigma: swap bits 2,3 of row index (K source only; V stays linear)
      const int rowk = (rowp & ~12) | ((rowp & 4) << 1) | ((rowp & 8) >> 1);
      gload_lds16(gK + (size_t)(kv0s + rowk) * E3_, &Ks[bf][r8 * 64]);
      gload_lds16(gV + (size_t)rowp * T_ + kv0s,    &Vs[bf][r8 * 64]);
    }
  };

  // Q B-fragments (pre-scaled): B[n=l16][k=quad*8+j], two k-chunks
  const short* qbase = qkv + (size_t)(b * T_ + q0w + l16) * E3_ + h * 64 + quad * 8;
  const s16x8 qf0 = *(const s16x8*)(qbase);
  const s16x8 qf1 = *(const s16x8*)(qbase + 32);

  f32x4 o[4]; f32x4 ol = (f32x4){0.f, 0.f, 0.f, 0.f};
#pragma unroll
  for (int j = 0; j < 4; j++) o[j] = (f32x4){0.f, 0.f, 0.f, 0.f};

  // prologue: stage kv tile 0 into buffer 0
  stage(0, 0);
  __syncthreads();

  for (int kv0 = 0, g = 0; kv0 <= q0b; kv0 += 64, g++) {
    const int cur = g & 1;

    // K A-fragments for this step
    s16x8 kf[2][4];
#pragma unroll
    for (int c = 0; c < 2; c++)
#pragma unroll
      for (int j = 0; j < 4; j++)
        kf[c][j] = *(const s16x8*)&Ks[cur][(j * 16 + l16) * 64 + (((c * 4 + quad) ^ swz) * 8)];

    // prefetch next tile's DMA (hidden under this step's compute)
    if (kv0 + 64 <= q0b) stage(kv0 + 64, cur ^ 1);

    // S^T tile: s[j][r] = score[kv_pos = 16j+4quad+r][q = q0w+l16]
    f32x4 s[4];
#pragma unroll
    for (int j = 0; j < 4; j++) s[j] = (f32x4){0.f, 0.f, 0.f, 0.f};
    __builtin_amdgcn_s_setprio(1);
#pragma unroll
    for (int c = 0; c < 2; c++)
#pragma unroll
      for (int j = 0; j < 4; j++)
        s[j] = __builtin_amdgcn_mfma_f32_16x16x32_bf16(kf[c][j], c == 0 ? qf0 : qf1, s[j], 0, 0, 0);
    __builtin_amdgcn_s_setprio(0);

    // mask only on the diagonal step; actual kv = 16j + 4*tau(quad) + r
    if (kv0 == q0b) {
      const int tq4 = ((quad & 1) << 3) | ((quad >> 1) << 2);
#pragma unroll
      for (int j = 0; j < 4; j++)
#pragma unroll
        for (int r = 0; r < 4; r++)
          if (j * 16 + tq4 + r > w * 16 + l16) s[j][r] = NEG_INF;
    }

    // exp2 in place — raw v_exp_f32 (single quarter-rate instruction each)
#pragma unroll
    for (int j = 0; j < 4; j++) {
      s[j][0] = __builtin_amdgcn_exp2f(s[j][0]);
      s[j][1] = __builtin_amdgcn_exp2f(s[j][1]);
      s[j][2] = __builtin_amdgcn_exp2f(s[j][2]);
      s[j][3] = __builtin_amdgcn_exp2f(s[j][3]);
    }

    // pack row pairs -> bf16 dwords (dst.lo = src0)
    int dj[4][2];
#pragma unroll
    for (int j = 0; j < 4; j++) {
      asm("v_cvt_pk_bf16_f32 %0, %1, %2" : "=v"(dj[j][0]) : "v"(s[j][0]), "v"(s[j][1]));
      asm("v_cvt_pk_bf16_f32 %0, %1, %2" : "=v"(dj[j][1]) : "v"(s[j][2]), "v"(s[j][3]));
    }

    // 2x permlane32_swap per kv32 chunk -> B-operand fragments in actual-kv order
    s16x8 F[2];
#pragma unroll
    for (int c = 0; c < 2; c++) {
      int x0 = dj[2 * c][0], y0 = dj[2 * c + 1][0];
      int x1 = dj[2 * c][1], y1 = dj[2 * c + 1][1];
      asm("v_permlane32_swap_b32 %0, %1" : "+v"(x0), "+v"(y0));
      asm("v_permlane32_swap_b32 %0, %1" : "+v"(x1), "+v"(y1));
      union { int i4[4]; s16x8 v; } u;
      u.i4[0] = x0; u.i4[1] = x1; u.i4[2] = y0; u.i4[3] = y1;
      F[c] = u.v;
    }

    // O^T += V^T P^T ; row sums via ones-MFMA (every reg = sum of lane's q)
    __builtin_amdgcn_s_setprio(1);
#pragma unroll
    for (int c = 0; c < 2; c++) {
      ol = __builtin_amdgcn_mfma_f32_16x16x32_bf16(ones, F[c], ol, 0, 0, 0);
#pragma unroll
      for (int j = 0; j < 4; j++) {
        const s16x8 vf = *(const s16x8*)&Vs[cur][(j * 16 + l16) * 64 + (((c * 4 + quad) ^ swz) * 8)];
        o[j] = __builtin_amdgcn_mfma_f32_16x16x32_bf16(vf, F[c], o[j], 0, 0, 0);
      }
    }
    __builtin_amdgcn_s_setprio(0);

    __syncthreads();  // drains prefetch (covered by compute) + WAR fence
  }

  // epilogue: lane owns q = q0w + l16; o[j][r] = O[q][d = 16j+4quad+r]
  const float inv = 1.0f / ol[0];
  const int q = q0w + l16;
  short* ob = attout + ((size_t)(b * T_ + q) * H_ + h) * 64 + quad * 4;
#pragma unroll
  for (int j = 0; j < 4; j++) {
    s16x4 pk;
#pragma unroll
    for (int r = 0; r < 4; r++) pk[r] = f2bf(o[j][r] * inv);
    *(s16x4*)&ob[16 * j] = pk;
  }
}

// ---------------- launch -----------------------------------------------------
extern "C" void kernel_launch(void* const* d_in, const int* in_sizes, int n_in,
                              void* d_out, int out_size, void* d_ws, size_t ws_size,
                              hipStream_t stream) {
  const float* x     = (const float*)d_in[0];   // [4096, 1024] fp32
  const float* wqkv  = (const float*)d_in[1];   // [3072, 1024] fp32
  const float* wproj = (const float*)d_in[2];   // [1024, 1024] fp32

  if (ws_size < 58720256u) return;
  short* ws     = (short*)d_ws;
  short* xb     = ws;                    // 4096*1024
  short* wqkvb  = xb + 4194304;          // 3072*1024
  short* wprojb = wqkvb + 3145728;       // 1024*1024
  short* qkv    = wprojb + 1048576;      // 4096*3072 (V third unused)
  short* vt     = qkv + 12582912;        // 2*16*64*2048
  short* attb   = vt + 4194304;          // 4096*1024

  castk_all<<<8192, 256, 0, stream>>>(x, wqkv, wproj, xb, wqkvb, wprojb);
  gemm256_qkv<<<dim3(12, 16), 512, 0, stream>>>(xb, wqkvb, qkv, vt);
  attn_kernel<<<dim3(32, 32), 256, 0, stream>>>(qkv, vt, attb);
  gemm_nt_128<0><<<dim3(8, 32), 256, 0, stream>>>(attb, wprojb, d_out, nullptr, 4096, 1024, 1024);
}

// Round 16
// 163.498 us; speedup vs baseline: 1.0727x; 1.0727x over previous
//
#include <hip/hip_runtime.h>
#include <stdint.h>
#include <stddef.h>

typedef __attribute__((ext_vector_type(8))) short s16x8;
typedef __attribute__((ext_vector_type(4))) short s16x4;
typedef __attribute__((ext_vector_type(4))) float f32x4;

#define B_  2
#define T_  2048
#define E_  1024
#define H_  16
#define E3_ 3072

// fp32 -> bf16, round-to-nearest-even
__device__ __forceinline__ short f2bf(float f) {
  union { float f; uint32_t u; } v; v.f = f;
  uint32_t u = v.u;
  return (short)((u + 0x7FFFu + ((u >> 16) & 1u)) >> 16);
}

// async global->LDS, 16B per lane; lds dest = wave-uniform base + lane*16
__device__ __forceinline__ void gload_lds16(const short* g, short* l) {
  __builtin_amdgcn_global_load_lds(
      (__attribute__((address_space(1))) void*)(const_cast<short*>(g)),
      (__attribute__((address_space(3))) void*)(l), 16, 0, 0);
}

// ---------------- merged cast kernel (x, w_qkv, w_proj in one launch) -------
// Q-rows of w_qkv (first E rows) pre-scaled by log2(e)/8 so attention can
// use raw v_exp_f32 directly on MFMA output.
__global__ void castk_all(const float* __restrict__ x, const float* __restrict__ wqkv,
                          const float* __restrict__ wproj, short* __restrict__ xb,
                          short* __restrict__ wqkvb, short* __restrict__ wprojb) {
  const int bid = blockIdx.x;
  const float* in; short* out; int i; float sc = 1.0f;
  if (bid < 4096)      { in = x;     out = xb;     i = bid * 256 + threadIdx.x; }
  else if (bid < 7168) { in = wqkv;  out = wqkvb;  i = (bid - 4096) * 256 + threadIdx.x;
                         if (i < 262144) sc = 0.18033688011112042f; }
  else                 { in = wproj; out = wprojb; i = (bid - 7168) * 256 + threadIdx.x; }
  const float4 v = ((const float4*)in)[i];
  s16x4 o;
  o[0] = f2bf(v.x * sc); o[1] = f2bf(v.y * sc);
  o[2] = f2bf(v.z * sc); o[3] = f2bf(v.w * sc);
  ((s16x4*)out)[i] = o;
}

// ---------------- NT GEMM: C[M,N] = A[M,K] * B[N,K]^T (bf16 in, fp32 acc) ---
// MODE 0: fp32 output, plain. MODE 2: qkv mode — bf16 output; V columns
// (col >= 2E) are written TRANSPOSED into vt[b,h,d,t] (packed s16x4 over 4
// consecutive t), Q/K columns go to the qkv buffer. Fuses the old vtrans.
// R15 lesson: a partial 256^2 phased port (1 block/CU, drain-0 vmcnt) ran
// 49us vs this structure's 28 — the m97-style 128^2 loop stays.
template <int MODE>
__global__ void gemm_nt_128(const short* __restrict__ A, const short* __restrict__ B,
                            void* __restrict__ Cv, short* __restrict__ vt,
                            int M, int N, int K) {
  __shared__ short As[128 * 32];
  __shared__ short Bs[128 * 32];
  const int tid  = threadIdx.x;
  const int lane = tid & 63;
  const int w    = tid >> 6;
  const int quad = lane >> 4;
  const int l16  = lane & 15;
  const int wm   = (w >> 1) * 64;
  const int wn   = (w & 1) * 64;
  const int bm   = blockIdx.y * 128;
  const int bn   = blockIdx.x * 128;

  f32x4 acc[4][4];
#pragma unroll
  for (int i = 0; i < 4; i++)
#pragma unroll
    for (int j = 0; j < 4; j++) acc[i][j] = (f32x4){0.f, 0.f, 0.f, 0.f};

  const int srow = w * 32 + (lane >> 2);
  const int scol = (lane & 3) * 8;
  const short* gA = A + (size_t)(bm + srow) * K + scol;
  const short* gB = B + (size_t)(bn + srow) * K + scol;
  short* lA = As + (w * 32) * 32;
  short* lB = Bs + (w * 32) * 32;

  for (int k0 = 0; k0 < K; k0 += 32) {
    __syncthreads();
    gload_lds16(gA + k0,          lA);
    gload_lds16(gA + 16 * K + k0, lA + 16 * 32);
    gload_lds16(gB + k0,          lB);
    gload_lds16(gB + 16 * K + k0, lB + 16 * 32);
    __syncthreads();

    s16x8 a[4], b[4];
#pragma unroll
    for (int i = 0; i < 4; i++)
      a[i] = *(const s16x8*)&As[(wm + i * 16 + l16) * 32 + quad * 8];
#pragma unroll
    for (int j = 0; j < 4; j++)
      b[j] = *(const s16x8*)&Bs[(wn + j * 16 + l16) * 32 + quad * 8];
#pragma unroll
    for (int i = 0; i < 4; i++)
#pragma unroll
      for (int j = 0; j < 4; j++)
        acc[i][j] = __builtin_amdgcn_mfma_f32_16x16x32_bf16(a[i], b[j], acc[i][j], 0, 0, 0);
  }

  if (MODE == 2 && bn >= 2 * E_) {
    // V block: write transposed to vt[b,h,d,t], 4 consecutive t per store
#pragma unroll
    for (int i = 0; i < 4; i++) {
      const int token = bm + wm + i * 16 + quad * 4;
      const int bb = token >> 11, t = token & (T_ - 1);
#pragma unroll
      for (int j = 0; j < 4; j++) {
        const int col = bn + wn + j * 16 + l16 - 2 * E_;  // h*64 + d
        s16x4 pk;
#pragma unroll
        for (int r = 0; r < 4; r++) pk[r] = f2bf(acc[i][j][r]);
        *(s16x4*)&vt[((size_t)(bb * H_ + (col >> 6)) * 64 + (col & 63)) * T_ + t] = pk;
      }
    }
  } else {
#pragma unroll
    for (int i = 0; i < 4; i++) {
      const int row0 = bm + wm + i * 16 + quad * 4;
#pragma unroll
      for (int j = 0; j < 4; j++) {
        const int col = bn + wn + j * 16 + l16;
#pragma unroll
        for (int r = 0; r < 4; r++) {
          const size_t idx = (size_t)(row0 + r) * N + col;
          if (MODE == 2) ((short*)Cv)[idx] = f2bf(acc[i][j][r]);
          else           ((float*)Cv)[idx] = acc[i][j][r];
        }
      }
    }
  }
}

// ---------------- flash attention (R12 — best verified, final) --------------
// 16q/wave, 4-wave 64q blocks, static 1024-block LPT-snake grid (4/CU),
// sigma K-store perm, tau diag mask, cvt_pk+permlane in-register P transpose,
// ones-MFMA row sums, raw v_exp_f32, 32KB LDS, setprio. Bank conflicts = 0.
// Refuted alternatives (measured): 2-wave blocks (R1), counted-vmcnt 3-buf
// (R3), 2x2 kv-split (R5, R14), direct-global K/V (R6), SM/PV interleave
// (R7), global queue (R8), 32q split items (R9/R11), per-XCD queues (R13).
__global__ void __launch_bounds__(256, 4)
attn_kernel(const short* __restrict__ qkv, const short* __restrict__ vt,
            short* __restrict__ attout) {
  __shared__ short Ks[2][64 * 64];  // [kv_pos][d], 16B-chunk swizzled, sigma row order
  __shared__ short Vs[2][64 * 64];  // [d][kv], 16B-chunk swizzled, linear kv
  const int tid  = threadIdx.x;
  const int lane = tid & 63;
  const int w    = tid >> 6;
  const int quad = lane >> 4;
  const int l16  = lane & 15;
  const int bh = blockIdx.x;
  const int b = bh >> 4, h = bh & 15;
  // LPT snake mapping: longest q-tiles dispatched first, per-CU sum uniform
  const int ya = blockIdx.y & 7, yb = blockIdx.y >> 3;
  const int qt = (3 - yb) * 8 + ((yb & 1) ? ya : (7 - ya));
  const int q0b = qt * 64;
  const int q0w = q0b + w * 16;
  const float NEG_INF = -__builtin_inff();

  const int srl = lane >> 3;
  const int sgc = ((lane & 7) ^ srl) * 8;
  const short* gK = qkv + (size_t)(b * T_) * E3_ + E_ + h * 64 + sgc;
  const short* gV = vt + (size_t)(bh * 64) * T_ + sgc;
  const int swz = (l16 & 7);

  s16x8 ones;
#pragma unroll
  for (int i = 0; i < 8; i++) ones[i] = (short)0x3F80;  // bf16 1.0

  auto stage = [&](int kv0s, int bf) {
#pragma unroll
    for (int i = 0; i < 2; i++) {
      const int r8 = w * 16 + i * 8;          // LDS row-chunk base
      const int rowp = r8 + srl;              // LDS row position
      // sigma: swap bits 2,3 of row index (K source only; V stays linear)
      const int rowk = (rowp & ~12) | ((rowp & 4) << 1) | ((rowp & 8) >> 1);
      gload_lds16(gK + (size_t)(kv0s + rowk) * E3_, &Ks[bf][r8 * 64]);
      gload_lds16(gV + (size_t)rowp * T_ + kv0s,    &Vs[bf][r8 * 64]);
    }
  };

  // Q B-fragments (pre-scaled): B[n=l16][k=quad*8+j], two k-chunks
  const short* qbase = qkv + (size_t)(b * T_ + q0w + l16) * E3_ + h * 64 + quad * 8;
  const s16x8 qf0 = *(const s16x8*)(qbase);
  const s16x8 qf1 = *(const s16x8*)(qbase + 32);

  f32x4 o[4]; f32x4 ol = (f32x4){0.f, 0.f, 0.f, 0.f};
#pragma unroll
  for (int j = 0; j < 4; j++) o[j] = (f32x4){0.f, 0.f, 0.f, 0.f};

  // prologue: stage kv tile 0 into buffer 0
  stage(0, 0);
  __syncthreads();

  for (int kv0 = 0, g = 0; kv0 <= q0b; kv0 += 64, g++) {
    const int cur = g & 1;

    // K A-fragments for this step
    s16x8 kf[2][4];
#pragma unroll
    for (int c = 0; c < 2; c++)
#pragma unroll
      for (int j = 0; j < 4; j++)
        kf[c][j] = *(const s16x8*)&Ks[cur][(j * 16 + l16) * 64 + (((c * 4 + quad) ^ swz) * 8)];

    // prefetch next tile's DMA (hidden under this step's compute)
    if (kv0 + 64 <= q0b) stage(kv0 + 64, cur ^ 1);

    // S^T tile: s[j][r] = score[kv_pos = 16j+4quad+r][q = q0w+l16]
    f32x4 s[4];
#pragma unroll
    for (int j = 0; j < 4; j++) s[j] = (f32x4){0.f, 0.f, 0.f, 0.f};
    __builtin_amdgcn_s_setprio(1);
#pragma unroll
    for (int c = 0; c < 2; c++)
#pragma unroll
      for (int j = 0; j < 4; j++)
        s[j] = __builtin_amdgcn_mfma_f32_16x16x32_bf16(kf[c][j], c == 0 ? qf0 : qf1, s[j], 0, 0, 0);
    __builtin_amdgcn_s_setprio(0);

    // mask only on the diagonal step; actual kv = 16j + 4*tau(quad) + r
    if (kv0 == q0b) {
      const int tq4 = ((quad & 1) << 3) | ((quad >> 1) << 2);
#pragma unroll
      for (int j = 0; j < 4; j++)
#pragma unroll
        for (int r = 0; r < 4; r++)
          if (j * 16 + tq4 + r > w * 16 + l16) s[j][r] = NEG_INF;
    }

    // exp2 in place — raw v_exp_f32 (single quarter-rate instruction each)
#pragma unroll
    for (int j = 0; j < 4; j++) {
      s[j][0] = __builtin_amdgcn_exp2f(s[j][0]);
      s[j][1] = __builtin_amdgcn_exp2f(s[j][1]);
      s[j][2] = __builtin_amdgcn_exp2f(s[j][2]);
      s[j][3] = __builtin_amdgcn_exp2f(s[j][3]);
    }

    // pack row pairs -> bf16 dwords (dst.lo = src0)
    int dj[4][2];
#pragma unroll
    for (int j = 0; j < 4; j++) {
      asm("v_cvt_pk_bf16_f32 %0, %1, %2" : "=v"(dj[j][0]) : "v"(s[j][0]), "v"(s[j][1]));
      asm("v_cvt_pk_bf16_f32 %0, %1, %2" : "=v"(dj[j][1]) : "v"(s[j][2]), "v"(s[j][3]));
    }

    // 2x permlane32_swap per kv32 chunk -> B-operand fragments in actual-kv order
    s16x8 F[2];
#pragma unroll
    for (int c = 0; c < 2; c++) {
      int x0 = dj[2 * c][0], y0 = dj[2 * c + 1][0];
      int x1 = dj[2 * c][1], y1 = dj[2 * c + 1][1];
      asm("v_permlane32_swap_b32 %0, %1" : "+v"(x0), "+v"(y0));
      asm("v_permlane32_swap_b32 %0, %1" : "+v"(x1), "+v"(y1));
      union { int i4[4]; s16x8 v; } u;
      u.i4[0] = x0; u.i4[1] = x1; u.i4[2] = y0; u.i4[3] = y1;
      F[c] = u.v;
    }

    // O^T += V^T P^T ; row sums via ones-MFMA (every reg = sum of lane's q)
    __builtin_amdgcn_s_setprio(1);
#pragma unroll
    for (int c = 0; c < 2; c++) {
      ol = __builtin_amdgcn_mfma_f32_16x16x32_bf16(ones, F[c], ol, 0, 0, 0);
#pragma unroll
      for (int j = 0; j < 4; j++) {
        const s16x8 vf = *(const s16x8*)&Vs[cur][(j * 16 + l16) * 64 + (((c * 4 + quad) ^ swz) * 8)];
        o[j] = __builtin_amdgcn_mfma_f32_16x16x32_bf16(vf, F[c], o[j], 0, 0, 0);
      }
    }
    __builtin_amdgcn_s_setprio(0);

    __syncthreads();  // drains prefetch (covered by compute) + WAR fence
  }

  // epilogue: lane owns q = q0w + l16; o[j][r] = O[q][d = 16j+4quad+r]
  const float inv = 1.0f / ol[0];
  const int q = q0w + l16;
  short* ob = attout + ((size_t)(b * T_ + q) * H_ + h) * 64 + quad * 4;
#pragma unroll
  for (int j = 0; j < 4; j++) {
    s16x4 pk;
#pragma unroll
    for (int r = 0; r < 4; r++) pk[r] = f2bf(o[j][r] * inv);
    *(s16x4*)&ob[16 * j] = pk;
  }
}

// ---------------- launch -----------------------------------------------------
extern "C" void kernel_launch(void* const* d_in, const int* in_sizes, int n_in,
                              void* d_out, int out_size, void* d_ws, size_t ws_size,
                              hipStream_t stream) {
  const float* x     = (const float*)d_in[0];   // [4096, 1024] fp32
  const float* wqkv  = (const float*)d_in[1];   // [3072, 1024] fp32
  const float* wproj = (const float*)d_in[2];   // [1024, 1024] fp32

  if (ws_size < 58720256u) return;
  short* ws     = (short*)d_ws;
  short* xb     = ws;                    // 4096*1024
  short* wqkvb  = xb + 4194304;          // 3072*1024
  short* wprojb = wqkvb + 3145728;       // 1024*1024
  short* qkv    = wprojb + 1048576;      // 4096*3072 (V third unused)
  short* vt     = qkv + 12582912;        // 2*16*64*2048
  short* attb   = vt + 4194304;          // 4096*1024

  castk_all<<<8192, 256, 0, stream>>>(x, wqkv, wproj, xb, wqkvb, wprojb);
  gemm_nt_128<2><<<dim3(24, 32), 256, 0, stream>>>(xb, wqkvb, qkv, vt, 4096, 3072, 1024);
  attn_kernel<<<dim3(32, 32), 256, 0, stream>>>(qkv, vt, attb);
  gemm_nt_128<0><<<dim3(8, 32), 256, 0, stream>>>(attb, wprojb, d_out, nullptr, 4096, 1024, 1024);
}